// Round 1
// baseline (3156.561 us; speedup 1.0000x reference)
//
#include <hip/hip_runtime.h>

// GCN 2-layer forward. All fp32.
// Factoring: out[d] = dinv[d] * ( sum_{e: src->d} g[src] + g[d] ) + bias,
// where g[i] = (h W)[i] * dinv[i].  Self-loop is the +g[d] term.

__global__ void k_deg_init(float* __restrict__ deg, int n) {
    int i = blockIdx.x * blockDim.x + threadIdx.x;
    if (i < n) deg[i] = 1.0f;  // self-loop contributes 1 to degree
}

__global__ void k_deg_edges(const int* __restrict__ dst, float* __restrict__ deg, int E) {
    int e = blockIdx.x * blockDim.x + threadIdx.x;
    if (e < E) atomicAdd(&deg[dst[e]], 1.0f);
}

__global__ void k_dinv(float* __restrict__ deg, int n) {
    int i = blockIdx.x * blockDim.x + threadIdx.x;
    if (i < n) deg[i] = rsqrtf(deg[i]);
}

// g1[row][o] = (x[row] @ W1)[o] * dinv[row]
// wave-per-row: lane l covers k in {4l..4l+3} u {256+4l..256+4l+3} (two float4 loads),
// W fragment in registers, reduce-scatter via shfl_xor.
__global__ __launch_bounds__(256) void k_gemm1(
    const float* __restrict__ x, const float* __restrict__ W1,
    const float* __restrict__ dinv, float* __restrict__ g1, int n) {
    const int lane = threadIdx.x & 63;
    const int wid  = blockIdx.x * (blockDim.x >> 6) + (threadIdx.x >> 6);
    const int nw   = gridDim.x * (blockDim.x >> 6);
    const float4* __restrict__ xv = (const float4*)x;
    const float4* __restrict__ wv = (const float4*)W1;

    float wreg[8][16];
#pragma unroll
    for (int j = 0; j < 4; ++j) {
#pragma unroll
        for (int q = 0; q < 4; ++q) {
            float4 wa = wv[(4 * lane + j) * 4 + q];
            wreg[j][4 * q + 0] = wa.x; wreg[j][4 * q + 1] = wa.y;
            wreg[j][4 * q + 2] = wa.z; wreg[j][4 * q + 3] = wa.w;
            float4 wb = wv[(256 + 4 * lane + j) * 4 + q];
            wreg[4 + j][4 * q + 0] = wb.x; wreg[4 + j][4 * q + 1] = wb.y;
            wreg[4 + j][4 * q + 2] = wb.z; wreg[4 + j][4 * q + 3] = wb.w;
        }
    }

    int row = wid;
    float4 a = make_float4(0.f, 0.f, 0.f, 0.f), b = a;
    if (row < n) { a = xv[row * 128 + lane]; b = xv[row * 128 + 64 + lane]; }
    for (; row < n; row += nw) {
        int nrow = row + nw;
        float4 a2 = a, b2 = b;
        if (nrow < n) { a2 = xv[nrow * 128 + lane]; b2 = xv[nrow * 128 + 64 + lane]; }

        float av[8] = {a.x, a.y, a.z, a.w, b.x, b.y, b.z, b.w};
        float acc[16];
#pragma unroll
        for (int o = 0; o < 16; ++o) acc[o] = 0.f;
#pragma unroll
        for (int j = 0; j < 8; ++j)
#pragma unroll
            for (int o = 0; o < 16; ++o) acc[o] = fmaf(av[j], wreg[j][o], acc[o]);

        // reduce-scatter: after 4 steps acc[0] holds output index (lane>>2)&15
        // summed over the 16 lanes sharing (lane&3).
#pragma unroll
        for (int i = 0; i < 8; ++i) {
            float send = (lane & 32) ? acc[i] : acc[i + 8];
            float recv = __shfl_xor(send, 32);
            float keep = (lane & 32) ? acc[i + 8] : acc[i];
            acc[i] = keep + recv;
        }
#pragma unroll
        for (int i = 0; i < 4; ++i) {
            float send = (lane & 16) ? acc[i] : acc[i + 4];
            float recv = __shfl_xor(send, 16);
            float keep = (lane & 16) ? acc[i + 4] : acc[i];
            acc[i] = keep + recv;
        }
#pragma unroll
        for (int i = 0; i < 2; ++i) {
            float send = (lane & 8) ? acc[i] : acc[i + 2];
            float recv = __shfl_xor(send, 8);
            float keep = (lane & 8) ? acc[i + 2] : acc[i];
            acc[i] = keep + recv;
        }
        {
            float send = (lane & 4) ? acc[0] : acc[1];
            float recv = __shfl_xor(send, 4);
            float keep = (lane & 4) ? acc[1] : acc[0];
            acc[0] = keep + recv;
        }
        float r = acc[0];
        r += __shfl_xor(r, 1);
        r += __shfl_xor(r, 2);
        if ((lane & 3) == 0) g1[(size_t)row * 16 + (lane >> 2)] = r * dinv[row];
        a = a2; b = b2;
    }
}

__global__ void k_agg16(const int* __restrict__ src, const int* __restrict__ dst,
                        const float* __restrict__ g, float* __restrict__ agg, int E) {
    int e = blockIdx.x * blockDim.x + threadIdx.x;
    if (e >= E) return;
    int s = src[e], d = dst[e];
    const float4* gs = (const float4*)(g + (size_t)s * 16);
    float4 v0 = gs[0], v1 = gs[1], v2 = gs[2], v3 = gs[3];
    float* ad = agg + (size_t)d * 16;
    atomicAdd(ad + 0,  v0.x); atomicAdd(ad + 1,  v0.y);
    atomicAdd(ad + 2,  v0.z); atomicAdd(ad + 3,  v0.w);
    atomicAdd(ad + 4,  v1.x); atomicAdd(ad + 5,  v1.y);
    atomicAdd(ad + 6,  v1.z); atomicAdd(ad + 7,  v1.w);
    atomicAdd(ad + 8,  v2.x); atomicAdd(ad + 9,  v2.y);
    atomicAdd(ad + 10, v2.z); atomicAdd(ad + 11, v2.w);
    atomicAdd(ad + 12, v3.x); atomicAdd(ad + 13, v3.y);
    atomicAdd(ad + 14, v3.z); atomicAdd(ad + 15, v3.w);
}

// h2 = relu(dinv*(agg1+g1) + b1); h3 = h2 @ W2; g2 = h3 * dinv
__global__ void k_h2h3(const float* __restrict__ g1, const float* __restrict__ agg1,
                       const float* __restrict__ dinv, const float* __restrict__ W2,
                       const float* __restrict__ b1, float* __restrict__ g2, int n) {
    int i = blockIdx.x * blockDim.x + threadIdx.x;
    if (i >= n) return;
    float dv = dinv[i];
    const float4* ga = (const float4*)(g1 + (size_t)i * 16);
    const float4* aa = (const float4*)(agg1 + (size_t)i * 16);
    float h2[16];
#pragma unroll
    for (int q = 0; q < 4; ++q) {
        float4 gv = ga[q], av = aa[q];
        h2[4 * q + 0] = fmaxf(fmaf(dv, gv.x + av.x, b1[4 * q + 0]), 0.f);
        h2[4 * q + 1] = fmaxf(fmaf(dv, gv.y + av.y, b1[4 * q + 1]), 0.f);
        h2[4 * q + 2] = fmaxf(fmaf(dv, gv.z + av.z, b1[4 * q + 2]), 0.f);
        h2[4 * q + 3] = fmaxf(fmaf(dv, gv.w + av.w, b1[4 * q + 3]), 0.f);
    }
    float c0 = 0.f, c1 = 0.f;
#pragma unroll
    for (int o = 0; o < 16; ++o) {
        c0 = fmaf(h2[o], W2[2 * o + 0], c0);
        c1 = fmaf(h2[o], W2[2 * o + 1], c1);
    }
    ((float2*)g2)[i] = make_float2(c0 * dv, c1 * dv);
}

__global__ void k_agg2(const int* __restrict__ src, const int* __restrict__ dst,
                       const float* __restrict__ g2, float* __restrict__ agg2, int E) {
    int e = blockIdx.x * blockDim.x + threadIdx.x;
    if (e >= E) return;
    int s = src[e], d = dst[e];
    float2 v = ((const float2*)g2)[s];
    atomicAdd(&agg2[2 * (size_t)d + 0], v.x);
    atomicAdd(&agg2[2 * (size_t)d + 1], v.y);
}

__global__ void k_final(const float* __restrict__ g2, const float* __restrict__ agg2,
                        const float* __restrict__ dinv, const float* __restrict__ b2,
                        float* __restrict__ out, int n) {
    int i = blockIdx.x * blockDim.x + threadIdx.x;
    if (i >= n) return;
    float dv = dinv[i];
    float2 g = ((const float2*)g2)[i];
    float2 a = ((const float2*)agg2)[i];
    ((float2*)out)[i] = make_float2(fmaf(dv, g.x + a.x, b2[0]),
                                    fmaf(dv, g.y + a.y, b2[1]));
}

extern "C" void kernel_launch(void* const* d_in, const int* in_sizes, int n_in,
                              void* d_out, int out_size, void* d_ws, size_t ws_size,
                              hipStream_t stream) {
    const float* x  = (const float*)d_in[0];
    const int*   ei = (const int*)d_in[1];
    const float* W1 = (const float*)d_in[2];
    const float* b1 = (const float*)d_in[3];
    const float* W2 = (const float*)d_in[4];
    const float* b2 = (const float*)d_in[5];
    float* out = (float*)d_out;

    const int n = in_sizes[0] / 512;
    const int E = in_sizes[1] / 2;
    const int* src = ei;
    const int* dst = ei + E;

    float* ws = (float*)d_ws;
    size_t off = 0;
    auto alloc = [&](size_t cnt) { float* p = ws + off; off += (cnt + 63) & ~(size_t)63; return p; };
    float* dinv = alloc((size_t)n);        // deg, then rsqrt in place
    float* g1   = alloc((size_t)n * 16);
    float* agg1 = alloc((size_t)n * 16);
    float* g2   = alloc((size_t)n * 2);
    float* agg2 = alloc((size_t)n * 2);

    hipMemsetAsync(agg1, 0, (size_t)n * 16 * sizeof(float), stream);
    hipMemsetAsync(agg2, 0, (size_t)n * 2 * sizeof(float), stream);

    int nb_n = (n + 255) / 256;
    int nb_e = (E + 255) / 256;

    k_deg_init<<<nb_n, 256, 0, stream>>>(dinv, n);
    k_deg_edges<<<nb_e, 256, 0, stream>>>(dst, dinv, E);
    k_dinv<<<nb_n, 256, 0, stream>>>(dinv, n);
    k_gemm1<<<1024, 256, 0, stream>>>(x, W1, dinv, g1, n);
    k_agg16<<<nb_e, 256, 0, stream>>>(src, dst, g1, agg1, E);
    k_h2h3<<<nb_n, 256, 0, stream>>>(g1, agg1, dinv, W2, b1, g2, n);
    k_agg2<<<nb_e, 256, 0, stream>>>(src, dst, g2, agg2, E);
    k_final<<<nb_n, 256, 0, stream>>>(g2, agg2, dinv, b2, out, n);
}

// Round 2
// 715.300 us; speedup vs baseline: 4.4129x; 4.4129x over previous
//
#include <hip/hip_runtime.h>

// GCN 2-layer forward, CSR-gather formulation. All fp32.
// out[d] = dinv[d] * ( sum_{e: src->d} g[src] + g[d] ) + bias,
// where g[i] = (h W)[i] * dinv[i]; self-loop is the +g[d] term.
// Aggregation via CSR (counting sort by dst) -> gather, no float atomics.

__global__ void k_hist(const int* __restrict__ dst, int* __restrict__ cnt, int E) {
    int e = blockIdx.x * blockDim.x + threadIdx.x;
    if (e < E) atomicAdd(&cnt[dst[e]], 1);
}

// Single-block exclusive scan of cnt -> row_start, fused dinv = rsqrt(cnt+1).
__global__ __launch_bounds__(1024) void k_scan_dinv(
    const int* __restrict__ cnt, int* __restrict__ row_start,
    float* __restrict__ dinv, int n) {
    __shared__ int lds[1024];
    const int t = threadIdx.x;
    const int C = (n + 1023) >> 10;
    const int lo = t * C, hi = min(n, lo + C);
    int s = 0;
    for (int i = lo; i < hi; ++i) s += cnt[i];
    lds[t] = s;
    __syncthreads();
    for (int off = 1; off < 1024; off <<= 1) {
        int v = (t >= off) ? lds[t - off] : 0;
        __syncthreads();
        lds[t] += v;
        __syncthreads();
    }
    int run = lds[t] - s;  // exclusive prefix for this chunk
    for (int i = lo; i < hi; ++i) {
        row_start[i] = run;
        run += cnt[i];
        dinv[i] = rsqrtf((float)cnt[i] + 1.0f);
    }
}

__global__ void k_scatter(const int* __restrict__ src, const int* __restrict__ dst,
                          const int* __restrict__ row_start, int* __restrict__ cursor,
                          int* __restrict__ csr, int E) {
    int e = blockIdx.x * blockDim.x + threadIdx.x;
    if (e >= E) return;
    int d = dst[e];
    int pos = row_start[d] + atomicAdd(&cursor[d], 1);
    csr[pos] = src[e];
}

// g1[row][o] = (x[row] @ W1)[o] * dinv[row]
// wave-per-row: lane l covers k in {4l..4l+3} u {256+4l..256+4l+3},
// W fragment in registers, reduce-scatter via shfl_xor.
__global__ __launch_bounds__(256) void k_gemm1(
    const float* __restrict__ x, const float* __restrict__ W1,
    const float* __restrict__ dinv, float* __restrict__ g1, int n) {
    const int lane = threadIdx.x & 63;
    const int wid  = blockIdx.x * (blockDim.x >> 6) + (threadIdx.x >> 6);
    const int nw   = gridDim.x * (blockDim.x >> 6);
    const float4* __restrict__ xv = (const float4*)x;
    const float4* __restrict__ wv = (const float4*)W1;

    float wreg[8][16];
#pragma unroll
    for (int j = 0; j < 4; ++j) {
#pragma unroll
        for (int q = 0; q < 4; ++q) {
            float4 wa = wv[(4 * lane + j) * 4 + q];
            wreg[j][4 * q + 0] = wa.x; wreg[j][4 * q + 1] = wa.y;
            wreg[j][4 * q + 2] = wa.z; wreg[j][4 * q + 3] = wa.w;
            float4 wb = wv[(256 + 4 * lane + j) * 4 + q];
            wreg[4 + j][4 * q + 0] = wb.x; wreg[4 + j][4 * q + 1] = wb.y;
            wreg[4 + j][4 * q + 2] = wb.z; wreg[4 + j][4 * q + 3] = wb.w;
        }
    }

    int row = wid;
    float4 a = make_float4(0.f, 0.f, 0.f, 0.f), b = a;
    if (row < n) { a = xv[row * 128 + lane]; b = xv[row * 128 + 64 + lane]; }
    for (; row < n; row += nw) {
        int nrow = row + nw;
        float4 a2 = a, b2 = b;
        if (nrow < n) { a2 = xv[nrow * 128 + lane]; b2 = xv[nrow * 128 + 64 + lane]; }

        float av[8] = {a.x, a.y, a.z, a.w, b.x, b.y, b.z, b.w};
        float acc[16];
#pragma unroll
        for (int o = 0; o < 16; ++o) acc[o] = 0.f;
#pragma unroll
        for (int j = 0; j < 8; ++j)
#pragma unroll
            for (int o = 0; o < 16; ++o) acc[o] = fmaf(av[j], wreg[j][o], acc[o]);

#pragma unroll
        for (int i = 0; i < 8; ++i) {
            float send = (lane & 32) ? acc[i] : acc[i + 8];
            float recv = __shfl_xor(send, 32);
            float keep = (lane & 32) ? acc[i + 8] : acc[i];
            acc[i] = keep + recv;
        }
#pragma unroll
        for (int i = 0; i < 4; ++i) {
            float send = (lane & 16) ? acc[i] : acc[i + 4];
            float recv = __shfl_xor(send, 16);
            float keep = (lane & 16) ? acc[i + 4] : acc[i];
            acc[i] = keep + recv;
        }
#pragma unroll
        for (int i = 0; i < 2; ++i) {
            float send = (lane & 8) ? acc[i] : acc[i + 2];
            float recv = __shfl_xor(send, 8);
            float keep = (lane & 8) ? acc[i + 2] : acc[i];
            acc[i] = keep + recv;
        }
        {
            float send = (lane & 4) ? acc[0] : acc[1];
            float recv = __shfl_xor(send, 4);
            float keep = (lane & 4) ? acc[1] : acc[0];
            acc[0] = keep + recv;
        }
        float r = acc[0];
        r += __shfl_xor(r, 1);
        r += __shfl_xor(r, 2);
        if ((lane & 3) == 0) g1[(size_t)row * 16 + (lane >> 2)] = r * dinv[row];
        a = a2; b = b2;
    }
}

// Wave per node: gather-sum g1 over CSR neighbors, fuse h2=relu(...), h3=h2@W2,
// g2 = h3*dinv. Lane layout: lane = eo*16 + f (4 edge slots x 16 features).
__global__ __launch_bounds__(256) void k_gather1(
    const int* __restrict__ row_start, const int* __restrict__ cnt,
    const int* __restrict__ csr, const float* __restrict__ g1,
    const float* __restrict__ dinv, const float* __restrict__ W2,
    const float* __restrict__ b1, float* __restrict__ g2, int n) {
    const int wid = blockIdx.x * 4 + (threadIdx.x >> 6);
    if (wid >= n) return;
    const int lane = threadIdx.x & 63;
    const int f = lane & 15, eo = lane >> 4;
    const int base = row_start[wid], deg = cnt[wid];
    float acc = 0.f;
    for (int j = eo; j < deg; j += 4) {
        int s = csr[base + j];
        acc += g1[(size_t)s * 16 + f];
    }
    acc += __shfl_xor(acc, 16);
    acc += __shfl_xor(acc, 32);
    const float dv = dinv[wid];
    float h2 = fmaxf(fmaf(dv, acc + g1[(size_t)wid * 16 + f], b1[f]), 0.f);
    float p0 = h2 * W2[2 * f], p1 = h2 * W2[2 * f + 1];
#pragma unroll
    for (int m = 1; m < 16; m <<= 1) {
        p0 += __shfl_xor(p0, m);
        p1 += __shfl_xor(p1, m);
    }
    if (lane == 0) ((float2*)g2)[wid] = make_float2(p0 * dv, p1 * dv);
}

// Wave per node: gather-sum float2 g2 over CSR neighbors, fuse bias -> out.
__global__ __launch_bounds__(256) void k_gather2(
    const int* __restrict__ row_start, const int* __restrict__ cnt,
    const int* __restrict__ csr, const float* __restrict__ g2,
    const float* __restrict__ dinv, const float* __restrict__ b2,
    float* __restrict__ out, int n) {
    const int wid = blockIdx.x * 4 + (threadIdx.x >> 6);
    if (wid >= n) return;
    const int lane = threadIdx.x & 63;
    const int base = row_start[wid], deg = cnt[wid];
    float a0 = 0.f, a1 = 0.f;
    for (int j = lane; j < deg; j += 64) {
        int s = csr[base + j];
        float2 v = ((const float2*)g2)[s];
        a0 += v.x; a1 += v.y;
    }
#pragma unroll
    for (int m = 1; m < 64; m <<= 1) {
        a0 += __shfl_xor(a0, m);
        a1 += __shfl_xor(a1, m);
    }
    if (lane == 0) {
        float dv = dinv[wid];
        float2 g = ((const float2*)g2)[wid];
        ((float2*)out)[wid] = make_float2(fmaf(dv, a0 + g.x, b2[0]),
                                          fmaf(dv, a1 + g.y, b2[1]));
    }
}

extern "C" void kernel_launch(void* const* d_in, const int* in_sizes, int n_in,
                              void* d_out, int out_size, void* d_ws, size_t ws_size,
                              hipStream_t stream) {
    const float* x  = (const float*)d_in[0];
    const int*   ei = (const int*)d_in[1];
    const float* W1 = (const float*)d_in[2];
    const float* b1 = (const float*)d_in[3];
    const float* W2 = (const float*)d_in[4];
    const float* b2 = (const float*)d_in[5];
    float* out = (float*)d_out;

    const int n = in_sizes[0] / 512;
    const int E = in_sizes[1] / 2;
    const int* src = ei;
    const int* dst = ei + E;

    char* ws = (char*)d_ws;
    size_t off = 0;
    auto alloc = [&](size_t bytes) {
        char* p = ws + off;
        off += (bytes + 255) & ~(size_t)255;
        return p;
    };
    float* dinv      = (float*)alloc((size_t)n * 4);
    float* g1        = (float*)alloc((size_t)n * 16 * 4);
    float* g2        = (float*)alloc((size_t)n * 2 * 4);
    int*   cnt       = (int*)alloc((size_t)n * 4);
    int*   row_start = (int*)alloc((size_t)n * 4);
    int*   cursor    = (int*)alloc((size_t)n * 4);
    int*   csr       = (int*)alloc((size_t)E * 4);

    hipMemsetAsync(cnt, 0, (size_t)n * 4, stream);
    hipMemsetAsync(cursor, 0, (size_t)n * 4, stream);

    const int nb_e = (E + 255) / 256;
    const int nb_w = (n + 3) / 4;  // wave-per-node kernels, 4 waves/block

    k_hist<<<nb_e, 256, 0, stream>>>(dst, cnt, E);
    k_scan_dinv<<<1, 1024, 0, stream>>>(cnt, row_start, dinv, n);
    k_scatter<<<nb_e, 256, 0, stream>>>(src, dst, row_start, cursor, csr, E);
    k_gemm1<<<1024, 256, 0, stream>>>(x, W1, dinv, g1, n);
    k_gather1<<<nb_w, 256, 0, stream>>>(row_start, cnt, csr, g1, dinv, W2, b1, g2, n);
    k_gather2<<<nb_w, 256, 0, stream>>>(row_start, cnt, csr, g2, dinv, b2, out, n);
}

// Round 3
// 516.722 us; speedup vs baseline: 6.1088x; 1.3843x over previous
//
#include <hip/hip_runtime.h>

// GCN 2-layer forward, CSR-gather formulation. All fp32.
// out[d] = dinv[d] * ( sum_{e: src->d} g[src] + g[d] ) + bias,
// where g[i] = (h W)[i] * dinv[i]; self-loop is the +g[d] term.
// Aggregation via CSR (counting sort by dst) -> gather, no float atomics.
// Scan is 3-stage parallel (partial sums -> scan block sums -> emit).

__global__ void k_hist(const int* __restrict__ dst, int* __restrict__ cnt, int E) {
    int e = blockIdx.x * blockDim.x + threadIdx.x;
    if (e < E) atomicAdd(&cnt[dst[e]], 1);
}

// Stage 1: per-block (1024-elem chunk) sum of cnt.
__global__ __launch_bounds__(256) void k_partial(
    const int* __restrict__ cnt, int* __restrict__ bs, int n) {
    __shared__ int lds[4];
    const int t = threadIdx.x;
    const int base = blockIdx.x * 1024 + t * 4;
    int s = 0;
#pragma unroll
    for (int j = 0; j < 4; ++j)
        if (base + j < n) s += cnt[base + j];
#pragma unroll
    for (int m = 1; m < 64; m <<= 1) s += __shfl_xor(s, m);
    if ((t & 63) == 0) lds[t >> 6] = s;
    __syncthreads();
    if (t == 0) bs[blockIdx.x] = lds[0] + lds[1] + lds[2] + lds[3];
}

// Stage 2: exclusive scan of block sums (nb <= 256), one small block.
__global__ __launch_bounds__(256) void k_scan_blocks(
    const int* __restrict__ bs, int* __restrict__ boff, int nb) {
    __shared__ int lds[256];
    const int t = threadIdx.x;
    int v = (t < nb) ? bs[t] : 0;
    lds[t] = v;
    __syncthreads();
    for (int off = 1; off < 256; off <<= 1) {
        int u = (t >= off) ? lds[t - off] : 0;
        __syncthreads();
        lds[t] += u;
        __syncthreads();
    }
    if (t < nb) boff[t] = lds[t] - v;
}

// Stage 3: in-block scan + block offset -> row_start; fused dinv.
__global__ __launch_bounds__(256) void k_emit(
    const int* __restrict__ cnt, const int* __restrict__ boff,
    int* __restrict__ row_start, float* __restrict__ dinv, int n) {
    __shared__ int lds[256];
    const int t = threadIdx.x;
    const int base = blockIdx.x * 1024 + t * 4;
    int c[4];
#pragma unroll
    for (int j = 0; j < 4; ++j) c[j] = (base + j < n) ? cnt[base + j] : 0;
    int s = c[0] + c[1] + c[2] + c[3];
    lds[t] = s;
    __syncthreads();
    for (int off = 1; off < 256; off <<= 1) {
        int u = (t >= off) ? lds[t - off] : 0;
        __syncthreads();
        lds[t] += u;
        __syncthreads();
    }
    int run = boff[blockIdx.x] + lds[t] - s;
#pragma unroll
    for (int j = 0; j < 4; ++j) {
        if (base + j < n) {
            row_start[base + j] = run;
            dinv[base + j] = rsqrtf((float)c[j] + 1.0f);
        }
        run += c[j];
    }
}

__global__ void k_scatter(const int* __restrict__ src, const int* __restrict__ dst,
                          const int* __restrict__ row_start, int* __restrict__ cursor,
                          int* __restrict__ csr, int E) {
    int e = blockIdx.x * blockDim.x + threadIdx.x;
    if (e >= E) return;
    int d = dst[e];
    int pos = row_start[d] + atomicAdd(&cursor[d], 1);
    csr[pos] = src[e];
}

// g1[row][o] = (x[row] @ W1)[o] * dinv[row]
// wave-per-row: lane l covers k in {4l..4l+3} u {256+4l..256+4l+3},
// W fragment in registers, reduce-scatter via shfl_xor.
__global__ __launch_bounds__(256) void k_gemm1(
    const float* __restrict__ x, const float* __restrict__ W1,
    const float* __restrict__ dinv, float* __restrict__ g1, int n) {
    const int lane = threadIdx.x & 63;
    const int wid  = blockIdx.x * (blockDim.x >> 6) + (threadIdx.x >> 6);
    const int nw   = gridDim.x * (blockDim.x >> 6);
    const float4* __restrict__ xv = (const float4*)x;
    const float4* __restrict__ wv = (const float4*)W1;

    float wreg[8][16];
#pragma unroll
    for (int j = 0; j < 4; ++j) {
#pragma unroll
        for (int q = 0; q < 4; ++q) {
            float4 wa = wv[(4 * lane + j) * 4 + q];
            wreg[j][4 * q + 0] = wa.x; wreg[j][4 * q + 1] = wa.y;
            wreg[j][4 * q + 2] = wa.z; wreg[j][4 * q + 3] = wa.w;
            float4 wb = wv[(256 + 4 * lane + j) * 4 + q];
            wreg[4 + j][4 * q + 0] = wb.x; wreg[4 + j][4 * q + 1] = wb.y;
            wreg[4 + j][4 * q + 2] = wb.z; wreg[4 + j][4 * q + 3] = wb.w;
        }
    }

    int row = wid;
    float4 a = make_float4(0.f, 0.f, 0.f, 0.f), b = a;
    if (row < n) { a = xv[row * 128 + lane]; b = xv[row * 128 + 64 + lane]; }
    for (; row < n; row += nw) {
        int nrow = row + nw;
        float4 a2 = a, b2 = b;
        if (nrow < n) { a2 = xv[nrow * 128 + lane]; b2 = xv[nrow * 128 + 64 + lane]; }

        float av[8] = {a.x, a.y, a.z, a.w, b.x, b.y, b.z, b.w};
        float acc[16];
#pragma unroll
        for (int o = 0; o < 16; ++o) acc[o] = 0.f;
#pragma unroll
        for (int j = 0; j < 8; ++j)
#pragma unroll
            for (int o = 0; o < 16; ++o) acc[o] = fmaf(av[j], wreg[j][o], acc[o]);

#pragma unroll
        for (int i = 0; i < 8; ++i) {
            float send = (lane & 32) ? acc[i] : acc[i + 8];
            float recv = __shfl_xor(send, 32);
            float keep = (lane & 32) ? acc[i + 8] : acc[i];
            acc[i] = keep + recv;
        }
#pragma unroll
        for (int i = 0; i < 4; ++i) {
            float send = (lane & 16) ? acc[i] : acc[i + 4];
            float recv = __shfl_xor(send, 16);
            float keep = (lane & 16) ? acc[i + 4] : acc[i];
            acc[i] = keep + recv;
        }
#pragma unroll
        for (int i = 0; i < 2; ++i) {
            float send = (lane & 8) ? acc[i] : acc[i + 2];
            float recv = __shfl_xor(send, 8);
            float keep = (lane & 8) ? acc[i + 2] : acc[i];
            acc[i] = keep + recv;
        }
        {
            float send = (lane & 4) ? acc[0] : acc[1];
            float recv = __shfl_xor(send, 4);
            float keep = (lane & 4) ? acc[1] : acc[0];
            acc[0] = keep + recv;
        }
        float r = acc[0];
        r += __shfl_xor(r, 1);
        r += __shfl_xor(r, 2);
        if ((lane & 3) == 0) g1[(size_t)row * 16 + (lane >> 2)] = r * dinv[row];
        a = a2; b = b2;
    }
}

// Wave per node: gather-sum g1 over CSR neighbors, fuse h2=relu(...), h3=h2@W2,
// g2 = h3*dinv. Lane layout: lane = eo*16 + f (4 edge slots x 16 features).
__global__ __launch_bounds__(256) void k_gather1(
    const int* __restrict__ row_start, const int* __restrict__ cnt,
    const int* __restrict__ csr, const float* __restrict__ g1,
    const float* __restrict__ dinv, const float* __restrict__ W2,
    const float* __restrict__ b1, float* __restrict__ g2, int n) {
    const int wid = blockIdx.x * 4 + (threadIdx.x >> 6);
    if (wid >= n) return;
    const int lane = threadIdx.x & 63;
    const int f = lane & 15, eo = lane >> 4;
    const int base = row_start[wid], deg = cnt[wid];
    float acc = 0.f;
    for (int j = eo; j < deg; j += 4) {
        int s = csr[base + j];
        acc += g1[(size_t)s * 16 + f];
    }
    acc += __shfl_xor(acc, 16);
    acc += __shfl_xor(acc, 32);
    const float dv = dinv[wid];
    float h2 = fmaxf(fmaf(dv, acc + g1[(size_t)wid * 16 + f], b1[f]), 0.f);
    float p0 = h2 * W2[2 * f], p1 = h2 * W2[2 * f + 1];
#pragma unroll
    for (int m = 1; m < 16; m <<= 1) {
        p0 += __shfl_xor(p0, m);
        p1 += __shfl_xor(p1, m);
    }
    if (lane == 0) ((float2*)g2)[wid] = make_float2(p0 * dv, p1 * dv);
}

// Wave per node: gather-sum float2 g2 over CSR neighbors, fuse bias -> out.
__global__ __launch_bounds__(256) void k_gather2(
    const int* __restrict__ row_start, const int* __restrict__ cnt,
    const int* __restrict__ csr, const float* __restrict__ g2,
    const float* __restrict__ dinv, const float* __restrict__ b2,
    float* __restrict__ out, int n) {
    const int wid = blockIdx.x * 4 + (threadIdx.x >> 6);
    if (wid >= n) return;
    const int lane = threadIdx.x & 63;
    const int base = row_start[wid], deg = cnt[wid];
    float a0 = 0.f, a1 = 0.f;
    for (int j = lane; j < deg; j += 64) {
        int s = csr[base + j];
        float2 v = ((const float2*)g2)[s];
        a0 += v.x; a1 += v.y;
    }
#pragma unroll
    for (int m = 1; m < 64; m <<= 1) {
        a0 += __shfl_xor(a0, m);
        a1 += __shfl_xor(a1, m);
    }
    if (lane == 0) {
        float dv = dinv[wid];
        float2 g = ((const float2*)g2)[wid];
        ((float2*)out)[wid] = make_float2(fmaf(dv, a0 + g.x, b2[0]),
                                          fmaf(dv, a1 + g.y, b2[1]));
    }
}

extern "C" void kernel_launch(void* const* d_in, const int* in_sizes, int n_in,
                              void* d_out, int out_size, void* d_ws, size_t ws_size,
                              hipStream_t stream) {
    const float* x  = (const float*)d_in[0];
    const int*   ei = (const int*)d_in[1];
    const float* W1 = (const float*)d_in[2];
    const float* b1 = (const float*)d_in[3];
    const float* W2 = (const float*)d_in[4];
    const float* b2 = (const float*)d_in[5];
    float* out = (float*)d_out;

    const int n = in_sizes[0] / 512;
    const int E = in_sizes[1] / 2;
    const int* src = ei;
    const int* dst = ei + E;

    char* ws = (char*)d_ws;
    size_t off = 0;
    auto alloc = [&](size_t bytes) {
        char* p = ws + off;
        off += (bytes + 255) & ~(size_t)255;
        return p;
    };
    float* dinv      = (float*)alloc((size_t)n * 4);
    float* g1        = (float*)alloc((size_t)n * 16 * 4);
    float* g2        = (float*)alloc((size_t)n * 2 * 4);
    int*   cnt       = (int*)alloc((size_t)n * 4);
    int*   row_start = (int*)alloc((size_t)n * 4);
    int*   cursor    = (int*)alloc((size_t)n * 4);
    int*   csr       = (int*)alloc((size_t)E * 4);

    const int nb_scan = (n + 1023) / 1024;  // 1024 elems per scan block (<=256 blocks)
    int* bs   = (int*)alloc((size_t)nb_scan * 4);
    int* boff = (int*)alloc((size_t)nb_scan * 4);

    hipMemsetAsync(cnt, 0, (size_t)n * 4, stream);
    hipMemsetAsync(cursor, 0, (size_t)n * 4, stream);

    const int nb_e = (E + 255) / 256;
    const int nb_w = (n + 3) / 4;  // wave-per-node kernels, 4 waves/block

    k_hist<<<nb_e, 256, 0, stream>>>(dst, cnt, E);
    k_partial<<<nb_scan, 256, 0, stream>>>(cnt, bs, n);
    k_scan_blocks<<<1, 256, 0, stream>>>(bs, boff, nb_scan);
    k_emit<<<nb_scan, 256, 0, stream>>>(cnt, boff, row_start, dinv, n);
    k_scatter<<<nb_e, 256, 0, stream>>>(src, dst, row_start, cursor, csr, E);
    k_gemm1<<<1024, 256, 0, stream>>>(x, W1, dinv, g1, n);
    k_gather1<<<nb_w, 256, 0, stream>>>(row_start, cnt, csr, g1, dinv, W2, b1, g2, n);
    k_gather2<<<nb_w, 256, 0, stream>>>(row_start, cnt, csr, g2, dinv, b2, out, n);
}

// Round 4
// 463.038 us; speedup vs baseline: 6.8171x; 1.1159x over previous
//
#include <hip/hip_runtime.h>

// GCN 2-layer forward, CSR-gather formulation. All fp32.
// out[d] = dinv[d] * ( sum_{e: src->d} g[src] + g[d] ) + bias,
// where g[i] = (h W)[i] * dinv[i]; self-loop is the +g[d] term.
// CSR built via two-pass binned partition (LDS histogram + bucket-local
// placement) to avoid random 4B scatter write amplification.

#define BKT_SHIFT 8            // 256 nodes per bucket
#define BIN_EPT 16             // edges per thread in k_bin (4096/block)

__global__ void k_hist(const int* __restrict__ dst, int* __restrict__ cnt, int E) {
    int e = blockIdx.x * blockDim.x + threadIdx.x;
    if (e < E) atomicAdd(&cnt[dst[e]], 1);
}

// Stage 1: per-block (1024-elem chunk) sum of cnt.
__global__ __launch_bounds__(256) void k_partial(
    const int* __restrict__ cnt, int* __restrict__ bs, int n) {
    __shared__ int lds[4];
    const int t = threadIdx.x;
    const int base = blockIdx.x * 1024 + t * 4;
    int s = 0;
#pragma unroll
    for (int j = 0; j < 4; ++j)
        if (base + j < n) s += cnt[base + j];
#pragma unroll
    for (int m = 1; m < 64; m <<= 1) s += __shfl_xor(s, m);
    if ((t & 63) == 0) lds[t >> 6] = s;
    __syncthreads();
    if (t == 0) bs[blockIdx.x] = lds[0] + lds[1] + lds[2] + lds[3];
}

// Stage 2: exclusive scan of block sums (nb <= 256), one small block.
__global__ __launch_bounds__(256) void k_scan_blocks(
    const int* __restrict__ bs, int* __restrict__ boff, int nb) {
    __shared__ int lds[256];
    const int t = threadIdx.x;
    int v = (t < nb) ? bs[t] : 0;
    lds[t] = v;
    __syncthreads();
    for (int off = 1; off < 256; off <<= 1) {
        int u = (t >= off) ? lds[t - off] : 0;
        __syncthreads();
        lds[t] += u;
        __syncthreads();
    }
    if (t < nb) boff[t] = lds[t] - v;
}

// Stage 3: in-block scan + block offset -> row_start; fused dinv.
__global__ __launch_bounds__(256) void k_emit(
    const int* __restrict__ cnt, const int* __restrict__ boff,
    int* __restrict__ row_start, float* __restrict__ dinv, int n) {
    __shared__ int lds[256];
    const int t = threadIdx.x;
    const int base = blockIdx.x * 1024 + t * 4;
    int c[4];
#pragma unroll
    for (int j = 0; j < 4; ++j) c[j] = (base + j < n) ? cnt[base + j] : 0;
    int s = c[0] + c[1] + c[2] + c[3];
    lds[t] = s;
    __syncthreads();
    for (int off = 1; off < 256; off <<= 1) {
        int u = (t >= off) ? lds[t - off] : 0;
        __syncthreads();
        lds[t] += u;
        __syncthreads();
    }
    int run = boff[blockIdx.x] + lds[t] - s;
#pragma unroll
    for (int j = 0; j < 4; ++j) {
        if (base + j < n) {
            row_start[base + j] = run;
            dinv[base + j] = rsqrtf((float)c[j] + 1.0f);
        }
        run += c[j];
    }
}

// Partition pass 1: bin (src,dst) pairs into per-bucket regions of `binned`
// (csr coordinates). LDS histogram -> one global reserve per (block,bucket)
// -> LDS cursor for local placement. Writes cluster into per-bucket runs.
__global__ __launch_bounds__(256) void k_bin(
    const int* __restrict__ src, const int* __restrict__ dst,
    const int* __restrict__ row_start, int* __restrict__ bucket_cursor,
    int2* __restrict__ binned, int E, int NB) {
    extern __shared__ int lds_pos[];  // NB ints
    const int t = threadIdx.x;
    const int base = blockIdx.x * (256 * BIN_EPT);
    for (int b = t; b < NB; b += 256) lds_pos[b] = 0;
    __syncthreads();
    int s_[BIN_EPT], d_[BIN_EPT];
#pragma unroll
    for (int j = 0; j < BIN_EPT; ++j) {
        int e = base + j * 256 + t;
        if (e < E) {
            s_[j] = src[e];
            d_[j] = dst[e];
            atomicAdd(&lds_pos[d_[j] >> BKT_SHIFT], 1);
        }
    }
    __syncthreads();
    for (int b = t; b < NB; b += 256) {
        int c = lds_pos[b];
        int g = (c > 0) ? atomicAdd(&bucket_cursor[b], c) : 0;
        lds_pos[b] = row_start[b << BKT_SHIFT] + g;  // global write base
    }
    __syncthreads();
#pragma unroll
    for (int j = 0; j < BIN_EPT; ++j) {
        int e = base + j * 256 + t;
        if (e < E) {
            int pos = atomicAdd(&lds_pos[d_[j] >> BKT_SHIFT], 1);
            binned[pos] = make_int2(s_[j], d_[j]);
        }
    }
}

// Partition pass 2: one block per bucket; cursor atomics + csr writes stay
// within a ~1KB / ~130KB slice -> cache-resident, full lines on eviction.
__global__ __launch_bounds__(256) void k_place(
    const int2* __restrict__ binned, const int* __restrict__ row_start,
    int* __restrict__ cursor, int* __restrict__ csr, int E, int n) {
    const int b = blockIdx.x;
    const int lo = row_start[b << BKT_SHIFT];
    const int nxt = (b + 1) << BKT_SHIFT;
    const int hi = (nxt < n) ? row_start[nxt] : E;
    for (int i = lo + threadIdx.x; i < hi; i += 256) {
        int2 p = binned[i];
        int r = atomicAdd(&cursor[p.y], 1);
        csr[row_start[p.y] + r] = p.x;
    }
}

// g1[row][o] = (x[row] @ W1)[o] * dinv[row]
// wave-per-row: lane l covers k in {4l..4l+3} u {256+4l..256+4l+3},
// W fragment in registers, reduce-scatter via shfl_xor.
__global__ __launch_bounds__(256) void k_gemm1(
    const float* __restrict__ x, const float* __restrict__ W1,
    const float* __restrict__ dinv, float* __restrict__ g1, int n) {
    const int lane = threadIdx.x & 63;
    const int wid  = blockIdx.x * (blockDim.x >> 6) + (threadIdx.x >> 6);
    const int nw   = gridDim.x * (blockDim.x >> 6);
    const float4* __restrict__ xv = (const float4*)x;
    const float4* __restrict__ wv = (const float4*)W1;

    float wreg[8][16];
#pragma unroll
    for (int j = 0; j < 4; ++j) {
#pragma unroll
        for (int q = 0; q < 4; ++q) {
            float4 wa = wv[(4 * lane + j) * 4 + q];
            wreg[j][4 * q + 0] = wa.x; wreg[j][4 * q + 1] = wa.y;
            wreg[j][4 * q + 2] = wa.z; wreg[j][4 * q + 3] = wa.w;
            float4 wb = wv[(256 + 4 * lane + j) * 4 + q];
            wreg[4 + j][4 * q + 0] = wb.x; wreg[4 + j][4 * q + 1] = wb.y;
            wreg[4 + j][4 * q + 2] = wb.z; wreg[4 + j][4 * q + 3] = wb.w;
        }
    }

    int row = wid;
    float4 a = make_float4(0.f, 0.f, 0.f, 0.f), b = a;
    if (row < n) { a = xv[row * 128 + lane]; b = xv[row * 128 + 64 + lane]; }
    for (; row < n; row += nw) {
        int nrow = row + nw;
        float4 a2 = a, b2 = b;
        if (nrow < n) { a2 = xv[nrow * 128 + lane]; b2 = xv[nrow * 128 + 64 + lane]; }

        float av[8] = {a.x, a.y, a.z, a.w, b.x, b.y, b.z, b.w};
        float acc[16];
#pragma unroll
        for (int o = 0; o < 16; ++o) acc[o] = 0.f;
#pragma unroll
        for (int j = 0; j < 8; ++j)
#pragma unroll
            for (int o = 0; o < 16; ++o) acc[o] = fmaf(av[j], wreg[j][o], acc[o]);

#pragma unroll
        for (int i = 0; i < 8; ++i) {
            float send = (lane & 32) ? acc[i] : acc[i + 8];
            float recv = __shfl_xor(send, 32);
            float keep = (lane & 32) ? acc[i + 8] : acc[i];
            acc[i] = keep + recv;
        }
#pragma unroll
        for (int i = 0; i < 4; ++i) {
            float send = (lane & 16) ? acc[i] : acc[i + 4];
            float recv = __shfl_xor(send, 16);
            float keep = (lane & 16) ? acc[i + 4] : acc[i];
            acc[i] = keep + recv;
        }
#pragma unroll
        for (int i = 0; i < 2; ++i) {
            float send = (lane & 8) ? acc[i] : acc[i + 2];
            float recv = __shfl_xor(send, 8);
            float keep = (lane & 8) ? acc[i + 2] : acc[i];
            acc[i] = keep + recv;
        }
        {
            float send = (lane & 4) ? acc[0] : acc[1];
            float recv = __shfl_xor(send, 4);
            float keep = (lane & 4) ? acc[1] : acc[0];
            acc[0] = keep + recv;
        }
        float r = acc[0];
        r += __shfl_xor(r, 1);
        r += __shfl_xor(r, 2);
        if ((lane & 3) == 0) g1[(size_t)row * 16 + (lane >> 2)] = r * dinv[row];
        a = a2; b = b2;
    }
}

// Wave per node: gather-sum g1 over CSR neighbors, fuse h2=relu(...), h3=h2@W2,
// g2 = h3*dinv. Lane layout: lane = eo*16 + f (4 edge slots x 16 features).
__global__ __launch_bounds__(256) void k_gather1(
    const int* __restrict__ row_start, const int* __restrict__ cnt,
    const int* __restrict__ csr, const float* __restrict__ g1,
    const float* __restrict__ dinv, const float* __restrict__ W2,
    const float* __restrict__ b1, float* __restrict__ g2, int n) {
    const int wid = blockIdx.x * 4 + (threadIdx.x >> 6);
    if (wid >= n) return;
    const int lane = threadIdx.x & 63;
    const int f = lane & 15, eo = lane >> 4;
    const int base = row_start[wid], deg = cnt[wid];
    float acc = 0.f;
    for (int j = eo; j < deg; j += 4) {
        int s = csr[base + j];
        acc += g1[(size_t)s * 16 + f];
    }
    acc += __shfl_xor(acc, 16);
    acc += __shfl_xor(acc, 32);
    const float dv = dinv[wid];
    float h2 = fmaxf(fmaf(dv, acc + g1[(size_t)wid * 16 + f], b1[f]), 0.f);
    float p0 = h2 * W2[2 * f], p1 = h2 * W2[2 * f + 1];
#pragma unroll
    for (int m = 1; m < 16; m <<= 1) {
        p0 += __shfl_xor(p0, m);
        p1 += __shfl_xor(p1, m);
    }
    if (lane == 0) ((float2*)g2)[wid] = make_float2(p0 * dv, p1 * dv);
}

// Wave per node: gather-sum float2 g2 over CSR neighbors, fuse bias -> out.
__global__ __launch_bounds__(256) void k_gather2(
    const int* __restrict__ row_start, const int* __restrict__ cnt,
    const int* __restrict__ csr, const float* __restrict__ g2,
    const float* __restrict__ dinv, const float* __restrict__ b2,
    float* __restrict__ out, int n) {
    const int wid = blockIdx.x * 4 + (threadIdx.x >> 6);
    if (wid >= n) return;
    const int lane = threadIdx.x & 63;
    const int base = row_start[wid], deg = cnt[wid];
    float a0 = 0.f, a1 = 0.f;
    for (int j = lane; j < deg; j += 64) {
        int s = csr[base + j];
        float2 v = ((const float2*)g2)[s];
        a0 += v.x; a1 += v.y;
    }
#pragma unroll
    for (int m = 1; m < 64; m <<= 1) {
        a0 += __shfl_xor(a0, m);
        a1 += __shfl_xor(a1, m);
    }
    if (lane == 0) {
        float dv = dinv[wid];
        float2 g = ((const float2*)g2)[wid];
        ((float2*)out)[wid] = make_float2(fmaf(dv, a0 + g.x, b2[0]),
                                          fmaf(dv, a1 + g.y, b2[1]));
    }
}

extern "C" void kernel_launch(void* const* d_in, const int* in_sizes, int n_in,
                              void* d_out, int out_size, void* d_ws, size_t ws_size,
                              hipStream_t stream) {
    const float* x  = (const float*)d_in[0];
    const int*   ei = (const int*)d_in[1];
    const float* W1 = (const float*)d_in[2];
    const float* b1 = (const float*)d_in[3];
    const float* W2 = (const float*)d_in[4];
    const float* b2 = (const float*)d_in[5];
    float* out = (float*)d_out;

    const int n = in_sizes[0] / 512;
    const int E = in_sizes[1] / 2;
    const int* src = ei;
    const int* dst = ei + E;

    const int NB = (n + (1 << BKT_SHIFT) - 1) >> BKT_SHIFT;  // buckets

    char* ws = (char*)d_ws;
    size_t off = 0;
    auto alloc = [&](size_t bytes) {
        char* p = ws + off;
        off += (bytes + 255) & ~(size_t)255;
        return p;
    };
    float* dinv      = (float*)alloc((size_t)n * 4);
    float* g1        = (float*)alloc((size_t)n * 16 * 4);
    float* g2        = (float*)alloc((size_t)n * 2 * 4);
    int*   cnt       = (int*)alloc((size_t)n * 4);
    int*   row_start = (int*)alloc((size_t)n * 4);
    int*   cursor    = (int*)alloc((size_t)n * 4);
    int*   csr       = (int*)alloc((size_t)E * 4);
    int2*  binned    = (int2*)alloc((size_t)E * 8);
    int*   bucket_cursor = (int*)alloc((size_t)NB * 4);

    const int nb_scan = (n + 1023) / 1024;  // <=256 blocks
    int* bs   = (int*)alloc((size_t)nb_scan * 4);
    int* boff = (int*)alloc((size_t)nb_scan * 4);

    hipMemsetAsync(cnt, 0, (size_t)n * 4, stream);
    hipMemsetAsync(cursor, 0, (size_t)n * 4, stream);
    hipMemsetAsync(bucket_cursor, 0, (size_t)NB * 4, stream);

    const int nb_e   = (E + 255) / 256;
    const int nb_bin = (E + 256 * BIN_EPT - 1) / (256 * BIN_EPT);
    const int nb_w   = (n + 3) / 4;  // wave-per-node kernels, 4 waves/block

    k_hist<<<nb_e, 256, 0, stream>>>(dst, cnt, E);
    k_partial<<<nb_scan, 256, 0, stream>>>(cnt, bs, n);
    k_scan_blocks<<<1, 256, 0, stream>>>(bs, boff, nb_scan);
    k_emit<<<nb_scan, 256, 0, stream>>>(cnt, boff, row_start, dinv, n);
    k_bin<<<nb_bin, 256, NB * 4, stream>>>(src, dst, row_start, bucket_cursor, binned, E, NB);
    k_place<<<NB, 256, 0, stream>>>(binned, row_start, cursor, csr, E, n);
    k_gemm1<<<1024, 256, 0, stream>>>(x, W1, dinv, g1, n);
    k_gather1<<<nb_w, 256, 0, stream>>>(row_start, cnt, csr, g1, dinv, W2, b1, g2, n);
    k_gather2<<<nb_w, 256, 0, stream>>>(row_start, cnt, csr, g2, dinv, b2, out, n);
}

// Round 5
// 314.576 us; speedup vs baseline: 10.0343x; 1.4719x over previous
//
#include <hip/hip_runtime.h>

// GCN 2-layer forward, CSR-gather formulation. All fp32.
// out[d] = dinv[d] * ( sum_{e: src->d} g[src] + g[d] ) + bias,
// where g[i] = (h W)[i] * dinv[i]; self-loop is the +g[d] term.
// CSR built via binned partition:
//   k_bhist: per-bucket histogram (LDS-aggregated)
//   k_scan_nb: scan bucket totals -> bucket_base
//   k_bin: scatter (src,dst) into bucket regions (LDS cursors per block)
//   k_place: per-bucket -> per-node counts/scan in LDS, emit row_start/cnt/
//            dinv and csr with LDS cursors. No global per-node atomics.

#define BKT_SHIFT 8            // 256 nodes per bucket
#define BIN_EPT 16             // edges per thread in binning kernels (4096/block)

// Per-bucket histogram of dst (LDS aggregated; ~NB global atomics per block).
__global__ __launch_bounds__(256) void k_bhist(
    const int* __restrict__ dst, int* __restrict__ bucket_cnt, int E, int NB) {
    extern __shared__ int h[];  // NB ints
    const int t = threadIdx.x;
    const int base = blockIdx.x * (256 * BIN_EPT);
    for (int b = t; b < NB; b += 256) h[b] = 0;
    __syncthreads();
#pragma unroll
    for (int j = 0; j < BIN_EPT; ++j) {
        int e = base + j * 256 + t;
        if (e < E) atomicAdd(&h[dst[e] >> BKT_SHIFT], 1);
    }
    __syncthreads();
    for (int b = t; b < NB; b += 256) {
        int c = h[b];
        if (c > 0) atomicAdd(&bucket_cnt[b], c);
    }
}

// Exclusive scan of NB (<=512) bucket counts -> bucket_base.
__global__ __launch_bounds__(512) void k_scan_nb(
    const int* __restrict__ bucket_cnt, int* __restrict__ bucket_base, int NB) {
    __shared__ int lds[512];
    const int t = threadIdx.x;
    int v = (t < NB) ? bucket_cnt[t] : 0;
    lds[t] = v;
    __syncthreads();
    for (int off = 1; off < 512; off <<= 1) {
        int u = (t >= off) ? lds[t - off] : 0;
        __syncthreads();
        lds[t] += u;
        __syncthreads();
    }
    if (t < NB) bucket_base[t] = lds[t] - v;
}

// Bin (src,dst) pairs into per-bucket regions of `binned`.
__global__ __launch_bounds__(256) void k_bin(
    const int* __restrict__ src, const int* __restrict__ dst,
    const int* __restrict__ bucket_base, int* __restrict__ bucket_cursor,
    int2* __restrict__ binned, int E, int NB) {
    extern __shared__ int lds_pos[];  // NB ints
    const int t = threadIdx.x;
    const int base = blockIdx.x * (256 * BIN_EPT);
    for (int b = t; b < NB; b += 256) lds_pos[b] = 0;
    __syncthreads();
    int s_[BIN_EPT], d_[BIN_EPT];
#pragma unroll
    for (int j = 0; j < BIN_EPT; ++j) {
        int e = base + j * 256 + t;
        if (e < E) {
            s_[j] = src[e];
            d_[j] = dst[e];
            atomicAdd(&lds_pos[d_[j] >> BKT_SHIFT], 1);
        }
    }
    __syncthreads();
    for (int b = t; b < NB; b += 256) {
        int c = lds_pos[b];
        int g = (c > 0) ? atomicAdd(&bucket_cursor[b], c) : 0;
        lds_pos[b] = bucket_base[b] + g;  // global write base for this block
    }
    __syncthreads();
#pragma unroll
    for (int j = 0; j < BIN_EPT; ++j) {
        int e = base + j * 256 + t;
        if (e < E) {
            int pos = atomicAdd(&lds_pos[d_[j] >> BKT_SHIFT], 1);
            binned[pos] = make_int2(s_[j], d_[j]);
        }
    }
}

// One block per bucket: per-node degree count in LDS, LDS scan ->
// row_start/cnt/dinv, then place csr with LDS cursors.
__global__ __launch_bounds__(256) void k_place(
    const int2* __restrict__ binned, const int* __restrict__ bucket_base,
    int* __restrict__ row_start, int* __restrict__ cnt, float* __restrict__ dinv,
    int* __restrict__ csr, int E, int n, int NB) {
    __shared__ int lcnt[256], sc[256];
    const int b = blockIdx.x;
    const int t = threadIdx.x;
    const int lo = bucket_base[b];
    const int hi = (b + 1 < NB) ? bucket_base[b + 1] : E;
    lcnt[t] = 0;
    __syncthreads();
    for (int i = lo + t; i < hi; i += 256)
        atomicAdd(&lcnt[binned[i].y & 255], 1);
    __syncthreads();
    int c = lcnt[t];
    sc[t] = c;
    __syncthreads();
    for (int off = 1; off < 256; off <<= 1) {
        int u = (t >= off) ? sc[t - off] : 0;
        __syncthreads();
        sc[t] += u;
        __syncthreads();
    }
    int excl = sc[t] - c;
    const int node = (b << BKT_SHIFT) + t;
    if (node < n) {
        row_start[node] = lo + excl;
        cnt[node] = c;
        dinv[node] = rsqrtf((float)c + 1.0f);
    }
    lcnt[t] = excl;  // becomes the local cursor
    __syncthreads();
    for (int i = lo + t; i < hi; i += 256) {
        int2 p = binned[i];
        int r = atomicAdd(&lcnt[p.y & 255], 1);
        csr[lo + r] = p.x;
    }
}

// g1[row][o] = (x[row] @ W1)[o] * dinv[row]
// wave-per-row: lane l covers k in {4l..4l+3} u {256+4l..256+4l+3},
// W fragment in registers, reduce-scatter via shfl_xor.
__global__ __launch_bounds__(256) void k_gemm1(
    const float* __restrict__ x, const float* __restrict__ W1,
    const float* __restrict__ dinv, float* __restrict__ g1, int n) {
    const int lane = threadIdx.x & 63;
    const int wid  = blockIdx.x * (blockDim.x >> 6) + (threadIdx.x >> 6);
    const int nw   = gridDim.x * (blockDim.x >> 6);
    const float4* __restrict__ xv = (const float4*)x;
    const float4* __restrict__ wv = (const float4*)W1;

    float wreg[8][16];
#pragma unroll
    for (int j = 0; j < 4; ++j) {
#pragma unroll
        for (int q = 0; q < 4; ++q) {
            float4 wa = wv[(4 * lane + j) * 4 + q];
            wreg[j][4 * q + 0] = wa.x; wreg[j][4 * q + 1] = wa.y;
            wreg[j][4 * q + 2] = wa.z; wreg[j][4 * q + 3] = wa.w;
            float4 wb = wv[(256 + 4 * lane + j) * 4 + q];
            wreg[4 + j][4 * q + 0] = wb.x; wreg[4 + j][4 * q + 1] = wb.y;
            wreg[4 + j][4 * q + 2] = wb.z; wreg[4 + j][4 * q + 3] = wb.w;
        }
    }

    int row = wid;
    float4 a = make_float4(0.f, 0.f, 0.f, 0.f), b = a;
    if (row < n) { a = xv[row * 128 + lane]; b = xv[row * 128 + 64 + lane]; }
    for (; row < n; row += nw) {
        int nrow = row + nw;
        float4 a2 = a, b2 = b;
        if (nrow < n) { a2 = xv[nrow * 128 + lane]; b2 = xv[nrow * 128 + 64 + lane]; }

        float av[8] = {a.x, a.y, a.z, a.w, b.x, b.y, b.z, b.w};
        float acc[16];
#pragma unroll
        for (int o = 0; o < 16; ++o) acc[o] = 0.f;
#pragma unroll
        for (int j = 0; j < 8; ++j)
#pragma unroll
            for (int o = 0; o < 16; ++o) acc[o] = fmaf(av[j], wreg[j][o], acc[o]);

#pragma unroll
        for (int i = 0; i < 8; ++i) {
            float send = (lane & 32) ? acc[i] : acc[i + 8];
            float recv = __shfl_xor(send, 32);
            float keep = (lane & 32) ? acc[i + 8] : acc[i];
            acc[i] = keep + recv;
        }
#pragma unroll
        for (int i = 0; i < 4; ++i) {
            float send = (lane & 16) ? acc[i] : acc[i + 4];
            float recv = __shfl_xor(send, 16);
            float keep = (lane & 16) ? acc[i + 4] : acc[i];
            acc[i] = keep + recv;
        }
#pragma unroll
        for (int i = 0; i < 2; ++i) {
            float send = (lane & 8) ? acc[i] : acc[i + 2];
            float recv = __shfl_xor(send, 8);
            float keep = (lane & 8) ? acc[i + 2] : acc[i];
            acc[i] = keep + recv;
        }
        {
            float send = (lane & 4) ? acc[0] : acc[1];
            float recv = __shfl_xor(send, 4);
            float keep = (lane & 4) ? acc[1] : acc[0];
            acc[0] = keep + recv;
        }
        float r = acc[0];
        r += __shfl_xor(r, 1);
        r += __shfl_xor(r, 2);
        if ((lane & 3) == 0) g1[(size_t)row * 16 + (lane >> 2)] = r * dinv[row];
        a = a2; b = b2;
    }
}

// Wave per node: gather-sum g1 over CSR neighbors, fuse h2=relu(...), h3=h2@W2,
// g2 = h3*dinv. Lane layout: lane = eo*16 + f (4 edge slots x 16 features).
__global__ __launch_bounds__(256) void k_gather1(
    const int* __restrict__ row_start, const int* __restrict__ cnt,
    const int* __restrict__ csr, const float* __restrict__ g1,
    const float* __restrict__ dinv, const float* __restrict__ W2,
    const float* __restrict__ b1, float* __restrict__ g2, int n) {
    const int wid = blockIdx.x * 4 + (threadIdx.x >> 6);
    if (wid >= n) return;
    const int lane = threadIdx.x & 63;
    const int f = lane & 15, eo = lane >> 4;
    const int base = row_start[wid], deg = cnt[wid];
    float acc = 0.f;
    for (int j = eo; j < deg; j += 4) {
        int s = csr[base + j];
        acc += g1[(size_t)s * 16 + f];
    }
    acc += __shfl_xor(acc, 16);
    acc += __shfl_xor(acc, 32);
    const float dv = dinv[wid];
    float h2 = fmaxf(fmaf(dv, acc + g1[(size_t)wid * 16 + f], b1[f]), 0.f);
    float p0 = h2 * W2[2 * f], p1 = h2 * W2[2 * f + 1];
#pragma unroll
    for (int m = 1; m < 16; m <<= 1) {
        p0 += __shfl_xor(p0, m);
        p1 += __shfl_xor(p1, m);
    }
    if (lane == 0) ((float2*)g2)[wid] = make_float2(p0 * dv, p1 * dv);
}

// Wave per node: gather-sum float2 g2 over CSR neighbors, fuse bias -> out.
__global__ __launch_bounds__(256) void k_gather2(
    const int* __restrict__ row_start, const int* __restrict__ cnt,
    const int* __restrict__ csr, const float* __restrict__ g2,
    const float* __restrict__ dinv, const float* __restrict__ b2,
    float* __restrict__ out, int n) {
    const int wid = blockIdx.x * 4 + (threadIdx.x >> 6);
    if (wid >= n) return;
    const int lane = threadIdx.x & 63;
    const int base = row_start[wid], deg = cnt[wid];
    float a0 = 0.f, a1 = 0.f;
    for (int j = lane; j < deg; j += 64) {
        int s = csr[base + j];
        float2 v = ((const float2*)g2)[s];
        a0 += v.x; a1 += v.y;
    }
#pragma unroll
    for (int m = 1; m < 64; m <<= 1) {
        a0 += __shfl_xor(a0, m);
        a1 += __shfl_xor(a1, m);
    }
    if (lane == 0) {
        float dv = dinv[wid];
        float2 g = ((const float2*)g2)[wid];
        ((float2*)out)[wid] = make_float2(fmaf(dv, a0 + g.x, b2[0]),
                                          fmaf(dv, a1 + g.y, b2[1]));
    }
}

extern "C" void kernel_launch(void* const* d_in, const int* in_sizes, int n_in,
                              void* d_out, int out_size, void* d_ws, size_t ws_size,
                              hipStream_t stream) {
    const float* x  = (const float*)d_in[0];
    const int*   ei = (const int*)d_in[1];
    const float* W1 = (const float*)d_in[2];
    const float* b1 = (const float*)d_in[3];
    const float* W2 = (const float*)d_in[4];
    const float* b2 = (const float*)d_in[5];
    float* out = (float*)d_out;

    const int n = in_sizes[0] / 512;
    const int E = in_sizes[1] / 2;
    const int* src = ei;
    const int* dst = ei + E;

    const int NB = (n + (1 << BKT_SHIFT) - 1) >> BKT_SHIFT;  // buckets (<=512)

    char* ws = (char*)d_ws;
    size_t off = 0;
    auto alloc = [&](size_t bytes) {
        char* p = ws + off;
        off += (bytes + 255) & ~(size_t)255;
        return p;
    };
    float* dinv      = (float*)alloc((size_t)n * 4);
    float* g1        = (float*)alloc((size_t)n * 16 * 4);
    float* g2        = (float*)alloc((size_t)n * 2 * 4);
    int*   cnt       = (int*)alloc((size_t)n * 4);
    int*   row_start = (int*)alloc((size_t)n * 4);
    int*   csr       = (int*)alloc((size_t)E * 4);
    int2*  binned    = (int2*)alloc((size_t)E * 8);
    int*   bucket_cnt    = (int*)alloc((size_t)NB * 4);
    int*   bucket_base   = (int*)alloc((size_t)NB * 4);
    int*   bucket_cursor = (int*)alloc((size_t)NB * 4);

    hipMemsetAsync(bucket_cnt, 0, (size_t)NB * 4, stream);
    hipMemsetAsync(bucket_cursor, 0, (size_t)NB * 4, stream);

    const int nb_bin = (E + 256 * BIN_EPT - 1) / (256 * BIN_EPT);
    const int nb_w   = (n + 3) / 4;  // wave-per-node kernels, 4 waves/block

    k_bhist<<<nb_bin, 256, NB * 4, stream>>>(dst, bucket_cnt, E, NB);
    k_scan_nb<<<1, 512, 0, stream>>>(bucket_cnt, bucket_base, NB);
    k_bin<<<nb_bin, 256, NB * 4, stream>>>(src, dst, bucket_base, bucket_cursor, binned, E, NB);
    k_place<<<NB, 256, 0, stream>>>(binned, bucket_base, row_start, cnt, dinv, csr, E, n, NB);
    k_gemm1<<<1024, 256, 0, stream>>>(x, W1, dinv, g1, n);
    k_gather1<<<nb_w, 256, 0, stream>>>(row_start, cnt, csr, g1, dinv, W2, b1, g2, n);
    k_gather2<<<nb_w, 256, 0, stream>>>(row_start, cnt, csr, g2, dinv, b2, out, n);
}